// Round 1
// baseline (3018.336 us; speedup 1.0000x reference)
//
#include <hip/hip_runtime.h>
#include <hip/hip_bf16.h>
#include <math.h>

#define NN    8192
#define FIN   512
#define HF    256
#define ME    65536

// ---------------- column sums of adj (+1 for self loop) -> deg ----------------
__global__ __launch_bounds__(256) void colsum_deg(const float* __restrict__ adj,
                                                  float* __restrict__ deg) {
    int c = blockIdx.x * 256 + threadIdx.x;
    int r0 = blockIdx.y * 512;
    float s = 0.f;
    for (int r = r0; r < r0 + 512; ++r) s += adj[(size_t)r * NN + c];
    if (blockIdx.y == 0) s += 1.f;
    atomicAdd(&deg[c], s);
}

// ---------------- generic fp32 GEMM C = A@B with optional epilogue ----------------
// C[r][c] = f( (A@B)[r][c] + addm[r][c] ) ; f = elu((v)/deg[r]) when deg!=null
// tile: 32 rows x 256 cols, BK=32, 256 threads, each thread 8 rows x 4 cols
__global__ __launch_bounds__(256) void gemm_ep(
    const float* __restrict__ A, const float* __restrict__ B,
    float* __restrict__ C, int M, int K, int N,
    const float* __restrict__ addm, const float* __restrict__ deg, int do_elu)
{
    __shared__ __align__(16) float sA[32][36];   // transposed: sA[k][m]
    __shared__ __align__(16) float sB[32][256];
    const int tid  = threadIdx.x;
    const int row0 = blockIdx.x * 32;
    const int col0 = blockIdx.y * 256;
    const int r0 = (tid >> 6) * 8;      // wave id * 8 rows
    const int c0 = (tid & 63) * 4;      // lane * 4 cols
    const int arow = tid >> 3;          // 0..31
    const int acol = (tid & 7) * 4;     // 0..28

    float acc[8][4];
    #pragma unroll
    for (int i = 0; i < 8; ++i)
        #pragma unroll
        for (int j = 0; j < 4; ++j) acc[i][j] = 0.f;

    for (int k0 = 0; k0 < K; k0 += 32) {
        float4 av = *(const float4*)(A + (size_t)(row0 + arow) * K + k0 + acol);
        float4 bv[8];
        #pragma unroll
        for (int i = 0; i < 8; ++i) {
            int idx = tid + i * 256;
            int br = idx >> 6, bc = (idx & 63) * 4;
            bv[i] = *(const float4*)(B + (size_t)(k0 + br) * N + col0 + bc);
        }
        __syncthreads();
        sA[acol + 0][arow] = av.x; sA[acol + 1][arow] = av.y;
        sA[acol + 2][arow] = av.z; sA[acol + 3][arow] = av.w;
        #pragma unroll
        for (int i = 0; i < 8; ++i) {
            int idx = tid + i * 256;
            int br = idx >> 6, bc = (idx & 63) * 4;
            *(float4*)&sB[br][bc] = bv[i];
        }
        __syncthreads();
        #pragma unroll 8
        for (int kk = 0; kk < 32; ++kk) {
            float4 a0 = *(const float4*)&sA[kk][r0];
            float4 a1 = *(const float4*)&sA[kk][r0 + 4];
            float4 b  = *(const float4*)&sB[kk][c0];
            float ar[8] = {a0.x, a0.y, a0.z, a0.w, a1.x, a1.y, a1.z, a1.w};
            float bc4[4] = {b.x, b.y, b.z, b.w};
            #pragma unroll
            for (int i = 0; i < 8; ++i)
                #pragma unroll
                for (int j = 0; j < 4; ++j)
                    acc[i][j] = fmaf(ar[i], bc4[j], acc[i][j]);
        }
    }
    #pragma unroll
    for (int i = 0; i < 8; ++i) {
        int r = row0 + r0 + i;
        size_t off = (size_t)r * N + col0 + c0;
        float4 v = make_float4(acc[i][0], acc[i][1], acc[i][2], acc[i][3]);
        if (addm) {
            float4 ad = *(const float4*)(addm + off);
            v.x += ad.x; v.y += ad.y; v.z += ad.z; v.w += ad.w;
        }
        if (deg) {
            float dinv = 1.0f / deg[r];
            v.x *= dinv; v.y *= dinv; v.z *= dinv; v.w *= dinv;
        }
        if (do_elu) {
            v.x = v.x > 0.f ? v.x : expm1f(v.x);
            v.y = v.y > 0.f ? v.y : expm1f(v.y);
            v.z = v.z > 0.f ? v.z : expm1f(v.z);
            v.w = v.w > 0.f ? v.w : expm1f(v.w);
        }
        *(float4*)(C + off) = v;
    }
}

// ---------------- wa2 = W @ a2  (512-vector) ----------------
__global__ __launch_bounds__(512) void wa2_kernel(const float* __restrict__ W,
                                                  const float* __restrict__ a2,
                                                  float* __restrict__ wa2) {
    int i = threadIdx.x;  // 512 threads
    float s = 0.f;
    for (int j = 0; j < HF; ++j) s += W[(size_t)i * HF + j] * a2[j];
    wa2[i] = s;
}

// ---------------- s2 = x @ wa2 ----------------
__global__ __launch_bounds__(256) void s2_kernel(const float* __restrict__ x,
                                                 const float* __restrict__ wa2,
                                                 float* __restrict__ s2) {
    int lane = threadIdx.x & 63, wv = threadIdx.x >> 6;
    int row = blockIdx.x * 4 + wv;
    const float4* xr = (const float4*)(x + (size_t)row * FIN);
    const float4* w4 = (const float4*)wa2;
    float s = 0.f;
    #pragma unroll
    for (int t = 0; t < 2; ++t) {
        float4 a = xr[lane + 64 * t], b = w4[lane + 64 * t];
        s += a.x * b.x + a.y * b.y + a.z * b.z + a.w * b.w;
    }
    #pragma unroll
    for (int off = 32; off > 0; off >>= 1) s += __shfl_down(s, off);
    if (lane == 0) s2[row] = s;
}

// ---------------- top-16 of s2 (global), tie-break smaller index ----------------
__global__ __launch_bounds__(256) void top16_kernel(const float* __restrict__ s2,
                                                    int* __restrict__ Tflag) {
    __shared__ float sv[NN];
    __shared__ float rv[256];
    __shared__ int   ri[256];
    int tid = threadIdx.x;
    for (int i = tid; i < NN; i += 256) sv[i] = s2[i];
    __syncthreads();
    for (int it = 0; it < 16; ++it) {
        float best = -INFINITY; int bi = NN;
        for (int i = tid; i < NN; i += 256) {
            float v = sv[i];
            if (v > best) { best = v; bi = i; }
        }
        rv[tid] = best; ri[tid] = bi;
        __syncthreads();
        for (int off = 128; off > 0; off >>= 1) {
            if (tid < off) {
                float v2 = rv[tid + off]; int i2 = ri[tid + off];
                if (v2 > rv[tid] || (v2 == rv[tid] && i2 < ri[tid])) {
                    rv[tid] = v2; ri[tid] = i2;
                }
            }
            __syncthreads();
        }
        if (tid == 0) { int w = ri[0]; Tflag[w] = 1; sv[w] = -INFINITY; }
        __syncthreads();
    }
}

// ---------------- column sums of Y: total[k] and sum over T rows ----------------
__global__ __launch_bounds__(256) void colsum_T(const float* __restrict__ Y,
                                                const int* __restrict__ Tflag,
                                                float* __restrict__ total,
                                                float* __restrict__ sumT) {
    int k = threadIdx.x;
    int r0 = blockIdx.x * 128;
    float t = 0.f, tt = 0.f;
    for (int r = r0; r < r0 + 128; ++r) {
        float v = Y[(size_t)r * HF + k];
        t += v;
        if (Tflag[r]) tt += v;
    }
    atomicAdd(&total[k], t);
    atomicAdd(&sumT[k], tt);
}

// ---------------- GCN2 propagate+elu, in place ----------------
__global__ __launch_bounds__(256) void gcn2_combine(float* __restrict__ Y,
                                                    const int* __restrict__ Tflag,
                                                    const float* __restrict__ sumT,
                                                    const float* __restrict__ total) {
    int idx = blockIdx.x * 256 + threadIdx.x;
    int i = idx >> 8, k = idx & 255;
    float v;
    if (Tflag[i]) v = total[k] / 8192.0f;
    else          v = (sumT[k] + Y[idx]) / 17.0f;
    Y[idx] = v > 0.f ? v : expm1f(v);
}

// ---------------- bilinear head + per-edge loss term ----------------
__global__ __launch_bounds__(256) void bilinear_kernel(
    const float* __restrict__ XB, const float* __restrict__ H,
    const float* __restrict__ Hs, const int* __restrict__ src,
    const int* __restrict__ dst, const float* __restrict__ labels,
    const float* __restrict__ bil_b,
    float* __restrict__ out_logits, float* __restrict__ out_pred,
    float* __restrict__ partials)
{
    __shared__ float wterm[4];
    int lane = threadIdx.x & 63;
    int wv = threadIdx.x >> 6;
    int e = blockIdx.x * 4 + wv;
    int s = src[e], d = dst[e];
    const float4* xb = (const float4*)(XB + (size_t)s * 512);
    const float4* h1 = (const float4*)(H + (size_t)d * HF);
    const float4* h2 = (const float4*)(Hs + (size_t)d * HF);
    float4 a = xb[lane], b = h1[lane];
    float sum = a.x * b.x + a.y * b.y + a.z * b.z + a.w * b.w;
    a = xb[64 + lane]; b = h2[lane];
    sum += a.x * b.x + a.y * b.y + a.z * b.z + a.w * b.w;
    #pragma unroll
    for (int off = 32; off > 0; off >>= 1) sum += __shfl_down(sum, off);
    if (lane == 0) {
        float l = sum + bil_b[0];
        out_logits[e] = l;
        out_pred[e] = (l >= 0.f) ? 1.f : 0.f;
        float lab = labels[e];
        wterm[wv] = fmaxf(l, 0.f) - l * lab + log1pf(expf(-fabsf(l)));
    }
    __syncthreads();
    if (threadIdx.x == 0)
        partials[blockIdx.x] = wterm[0] + wterm[1] + wterm[2] + wterm[3];
}

__global__ __launch_bounds__(256) void loss_finalize(const float* __restrict__ partials,
                                                     float* __restrict__ out) {
    __shared__ float s[256];
    int tid = threadIdx.x;
    float t = 0.f;
    for (int i = tid; i < ME / 4; i += 256) t += partials[i];
    s[tid] = t; __syncthreads();
    for (int off = 128; off > 0; off >>= 1) {
        if (tid < off) s[tid] += s[tid + off];
        __syncthreads();
    }
    if (tid == 0) out[0] = s[0] * (1.0f / (float)ME);
}

// ---------------- launch ----------------
extern "C" void kernel_launch(void* const* d_in, const int* in_sizes, int n_in,
                              void* d_out, int out_size, void* d_ws, size_t ws_size,
                              hipStream_t stream) {
    const int*   src    = (const int*)d_in[0];
    const int*   dst    = (const int*)d_in[1];
    const float* labels = (const float*)d_in[2];
    const float* adj    = (const float*)d_in[3];
    const float* x      = (const float*)d_in[4];
    const float* W1_0   = (const float*)d_in[5];
    const float* W1_1   = (const float*)d_in[6];
    const float* W2_0   = (const float*)d_in[7];
    const float* W2_1   = (const float*)d_in[8];
    const float* W      = (const float*)d_in[9];
    // a1 (d_in[10]) is unused: it never affects the top-k mask.
    const float* a2     = (const float*)d_in[11];
    const float* bilw   = (const float*)d_in[12];
    const float* bilb   = (const float*)d_in[13];

    float* w = (float*)d_ws;
    // float offsets
    const size_t O_DEG   = 0;          // 8192
    const size_t O_S2    = 8192;       // 8192
    const size_t O_WA2   = 16384;      // 512
    const size_t O_SUMT  = 16896;      // 256
    const size_t O_TOT   = 17152;      // 256
    const size_t O_SUM2T = 17408;      // 256
    const size_t O_TOT2  = 17664;      // 256
    const size_t O_PART  = 17920;      // 16384
    const size_t O_TFLAG = 34304;      // 8192 ints
    const size_t O_BUFA  = 65536;      // 8192*256
    const size_t O_BUFB  = O_BUFA + (size_t)NN * HF;
    const size_t O_BUFC  = O_BUFB + (size_t)NN * HF;
    const size_t O_BUFD  = O_BUFC + (size_t)NN * HF;   // 8192*512

    float* deg   = w + O_DEG;
    float* s2v   = w + O_S2;
    float* wa2   = w + O_WA2;
    float* sumT  = w + O_SUMT;
    float* total = w + O_TOT;
    float* sum2T = w + O_SUM2T;
    float* tot2  = w + O_TOT2;
    float* part  = w + O_PART;
    int*   Tflag = (int*)(w + O_TFLAG);
    float* bufA  = w + O_BUFA;
    float* bufB  = w + O_BUFB;
    float* bufC  = w + O_BUFC;
    float* bufD  = w + O_BUFD;

    float* out       = (float*)d_out;
    float* out_logit = out + 1;
    float* out_pred  = out + 1 + ME;

    hipMemsetAsync(deg, 0, NN * sizeof(float), stream);
    hipMemsetAsync(sumT, 0, 1024 * sizeof(float), stream);  // sumT..tot2
    hipMemsetAsync(Tflag, 0, NN * sizeof(int), stream);

    // deg = colsum(adj) + 1
    colsum_deg<<<dim3(32, 16), 256, 0, stream>>>(adj, deg);

    // GCN1: H1 = elu((adj@XW1 + XW1)/deg) ; H = elu((adj@XW2 + XW2)/deg)
    gemm_ep<<<dim3(256, 1), 256, 0, stream>>>(x, W1_0, bufA, NN, FIN, HF, nullptr, nullptr, 0);
    gemm_ep<<<dim3(256, 1), 256, 0, stream>>>(adj, bufA, bufB, NN, NN, HF, bufA, deg, 1);
    gemm_ep<<<dim3(256, 1), 256, 0, stream>>>(bufB, W1_1, bufA, NN, HF, HF, nullptr, nullptr, 0);
    gemm_ep<<<dim3(256, 1), 256, 0, stream>>>(adj, bufA, bufB, NN, NN, HF, bufA, deg, 1);
    // bufB = H (persist)

    // similarity graph: only the ordering of s2 = x @ (W @ a2) matters
    wa2_kernel<<<1, 512, 0, stream>>>(W, a2, wa2);
    s2_kernel<<<NN / 4, 256, 0, stream>>>(x, wa2, s2v);
    top16_kernel<<<1, 256, 0, stream>>>(s2v, Tflag);

    // GCN2 via column sums
    gemm_ep<<<dim3(256, 1), 256, 0, stream>>>(x, W2_0, bufA, NN, FIN, HF, nullptr, nullptr, 0);
    colsum_T<<<64, 256, 0, stream>>>(bufA, Tflag, total, sumT);
    gcn2_combine<<<NN, 256, 0, stream>>>(bufA, Tflag, sumT, total);          // bufA = Z1
    gemm_ep<<<dim3(256, 1), 256, 0, stream>>>(bufA, W2_1, bufC, NN, HF, HF, nullptr, nullptr, 0);
    colsum_T<<<64, 256, 0, stream>>>(bufC, Tflag, tot2, sum2T);
    gcn2_combine<<<NN, 256, 0, stream>>>(bufC, Tflag, sum2T, tot2);          // bufC = H_

    // bilinear head: XB = x @ B, logits[e] = XB[src]·[H|H_][dst] + b
    gemm_ep<<<dim3(256, 2), 256, 0, stream>>>(x, bilw, bufD, NN, FIN, 512, nullptr, nullptr, 0);
    bilinear_kernel<<<ME / 4, 256, 0, stream>>>(bufD, bufB, bufC, src, dst, labels, bilb,
                                                out_logit, out_pred, part);
    loss_finalize<<<1, 256, 0, stream>>>(part, out);
}

// Round 3
// 1392.825 us; speedup vs baseline: 2.1671x; 2.1671x over previous
//
#include <hip/hip_runtime.h>
#include <math.h>

#define NN    8192
#define FIN   512
#define HF    256
#define ME    65536

typedef short bf16x8 __attribute__((ext_vector_type(8)));
typedef float f32x4  __attribute__((ext_vector_type(4)));

__device__ inline unsigned short f2bf(float f) {
    unsigned u = __builtin_bit_cast(unsigned, f);
    u += 0x7FFF + ((u >> 16) & 1);
    return (unsigned short)(u >> 16);
}
__device__ inline float bf2f(unsigned short h) {
    return __builtin_bit_cast(float, (unsigned)h << 16);
}
__device__ inline void split_bf(float v, short& hi, short& lo) {
    unsigned short h = f2bf(v);
    hi = (short)h;
    lo = (short)f2bf(v - bf2f(h));
}
__device__ inline float eluf(float v) { return v > 0.f ? v : expm1f(v); }

// ---------------- column sums of adj (+1 for self loop) -> deg ----------------
__global__ __launch_bounds__(256) void colsum_deg(const float* __restrict__ adj,
                                                  float* __restrict__ deg) {
    int c = blockIdx.x * 256 + threadIdx.x;
    int r0 = blockIdx.y * 512;
    float s = 0.f;
    for (int r = r0; r < r0 + 512; ++r) s += adj[(size_t)r * NN + c];
    if (blockIdx.y == 0) s += 1.f;
    atomicAdd(&deg[c], s);
}

// ---------------- W [K][N] fp32 -> split bf16 Wt_hi/lo [N][K] ----------------
__global__ __launch_bounds__(256) void trans_w_split(const float* __restrict__ src,
                                                     short* __restrict__ dsth,
                                                     short* __restrict__ dstl,
                                                     int K, int lgN) {
    int idx = blockIdx.x * 256 + threadIdx.x;
    int N = 1 << lgN;
    int k = idx >> lgN, n = idx & (N - 1);
    short h, l;
    split_bf(src[idx], h, l);
    dsth[(size_t)n * K + k] = h;
    dstl[(size_t)n * K + k] = l;
}

// ---------------- split-bf16 MFMA GEMM: C = A(fp32) @ Bt^T, + transposed split out
// BM=64, BN=128, BK=64, 256 threads (4 waves 2x2, wave tile 32x64)
__global__ __launch_bounds__(256) void mfma_split(
    const float* __restrict__ A, const short* __restrict__ BtH,
    const short* __restrict__ BtL, float* __restrict__ C,
    short* __restrict__ CtH, short* __restrict__ CtL, int M, int K, int N)
{
    __shared__ __align__(16) char smem[49152];
    short* sAh = (short*)smem;                 // 64*64
    short* sAl = (short*)(smem + 8192);
    short* sBh = (short*)(smem + 16384);       // 128*64
    short* sBl = (short*)(smem + 32768);
    float* sT  = (float*)smem;                 // 64*136 fp32 overlay (epilogue)
    const int tid = threadIdx.x, lane = tid & 63, wid = tid >> 6;
    const int wm = wid >> 1, wn = wid & 1;
    const int m0 = blockIdx.x * 64, n0 = blockIdx.y * 128;
    const int lhi = lane >> 4, llo = lane & 15;

    f32x4 acc[2][4];
    #pragma unroll
    for (int mi = 0; mi < 2; ++mi)
        #pragma unroll
        for (int ni = 0; ni < 4; ++ni) acc[mi][ni] = (f32x4){0.f, 0.f, 0.f, 0.f};

    for (int kt = 0; kt < K; kt += 64) {
        float4 av[4];
        #pragma unroll
        for (int it = 0; it < 4; ++it) {
            int h = tid + 256 * it;
            int r = h >> 4, hs = h & 15, slot = hs >> 1, half = hs & 1;
            int gk = ((slot ^ (r & 7)) * 2 + half) * 4;
            av[it] = *(const float4*)(A + (size_t)(m0 + r) * K + kt + gk);
        }
        int4 bvh[4], bvl[4];
        #pragma unroll
        for (int it = 0; it < 4; ++it) {
            int u = tid + 256 * it;
            int c = u >> 3, s = u & 7;
            size_t off = (size_t)(n0 + c) * K + kt + (s ^ (c & 7)) * 8;
            bvh[it] = *(const int4*)(BtH + off);
            bvl[it] = *(const int4*)(BtL + off);
        }
        __syncthreads();
        #pragma unroll
        for (int it = 0; it < 4; ++it) {
            int h = tid + 256 * it;
            short4 wh, wl;
            split_bf(av[it].x, wh.x, wl.x); split_bf(av[it].y, wh.y, wl.y);
            split_bf(av[it].z, wh.z, wl.z); split_bf(av[it].w, wh.w, wl.w);
            *(short4*)((char*)sAh + h * 8) = wh;
            *(short4*)((char*)sAl + h * 8) = wl;
        }
        #pragma unroll
        for (int it = 0; it < 4; ++it) {
            int u = tid + 256 * it;
            *(int4*)((char*)sBh + u * 16) = bvh[it];
            *(int4*)((char*)sBl + u * 16) = bvl[it];
        }
        __syncthreads();
        #pragma unroll
        for (int ks = 0; ks < 2; ++ks) {
            bf16x8 afh[2], afl[2], bfh[4], bfl[4];
            #pragma unroll
            for (int mi = 0; mi < 2; ++mi) {
                int R = wm * 32 + mi * 16 + llo;
                int boff = R * 128 + (((ks * 4 + lhi) ^ (R & 7)) << 4);
                afh[mi] = *(const bf16x8*)((const char*)sAh + boff);
                afl[mi] = *(const bf16x8*)((const char*)sAl + boff);
            }
            #pragma unroll
            for (int ni = 0; ni < 4; ++ni) {
                int Cc = wn * 64 + ni * 16 + llo;
                int boff = Cc * 128 + (((ks * 4 + lhi) ^ (Cc & 7)) << 4);
                bfh[ni] = *(const bf16x8*)((const char*)sBh + boff);
                bfl[ni] = *(const bf16x8*)((const char*)sBl + boff);
            }
            #pragma unroll
            for (int mi = 0; mi < 2; ++mi)
                #pragma unroll
                for (int ni = 0; ni < 4; ++ni) {
                    acc[mi][ni] = __builtin_amdgcn_mfma_f32_16x16x32_bf16(afh[mi], bfh[ni], acc[mi][ni], 0, 0, 0);
                    acc[mi][ni] = __builtin_amdgcn_mfma_f32_16x16x32_bf16(afh[mi], bfl[ni], acc[mi][ni], 0, 0, 0);
                    acc[mi][ni] = __builtin_amdgcn_mfma_f32_16x16x32_bf16(afl[mi], bfh[ni], acc[mi][ni], 0, 0, 0);
                }
        }
    }

    __syncthreads();   // LDS reads done; overlay sT
    #pragma unroll
    for (int mi = 0; mi < 2; ++mi)
        #pragma unroll
        for (int ni = 0; ni < 4; ++ni) {
            int lr = wm * 32 + mi * 16 + lhi * 4;
            int lc = wn * 64 + ni * 16 + llo;
            int R0 = m0 + lr;
            int Cc = n0 + lc;
            #pragma unroll
            for (int r = 0; r < 4; ++r) {
                C[(size_t)(R0 + r) * N + Cc] = acc[mi][ni][r];
                sT[(lr + r) * 136 + lc] = acc[mi][ni][r];
            }
        }
    __syncthreads();
    int c = tid >> 1, ih = (tid & 1) * 32;
    short bh[32], bl[32];
    #pragma unroll
    for (int j = 0; j < 32; ++j)
        split_bf(sT[(ih + j) * 136 + c], bh[j], bl[j]);
    int4* dh = (int4*)(CtH + (size_t)(n0 + c) * M + m0 + ih);
    int4* dl = (int4*)(CtL + (size_t)(n0 + c) * M + m0 + ih);
    #pragma unroll
    for (int q = 0; q < 4; ++q) { dh[q] = ((int4*)bh)[q]; dl[q] = ((int4*)bl)[q]; }
}

// ---------------- adj propagate partial (split-bf16): part = adj[:,kchunk] @ Y[kchunk,:]
// BM=64, BN=256(=HF), BK=64, 512 threads (8 waves 2x4, wave tile 32x64)
__global__ __launch_bounds__(512) void adj_prop(const float* __restrict__ adj,
                                                const short* __restrict__ YtH,
                                                const short* __restrict__ YtL,
                                                float* __restrict__ part0,
                                                float* __restrict__ part1)
{
    __shared__ __align__(16) char smem[81920];
    short* sAh = (short*)smem;                 // 64*64
    short* sAl = (short*)(smem + 8192);
    short* sBh = (short*)(smem + 16384);       // 256*64
    short* sBl = (short*)(smem + 49152);
    const int tid = threadIdx.x, lane = tid & 63, wid = tid >> 6;
    const int wm = wid >> 2, wn = wid & 3;
    const int i0 = blockIdx.x * 64;
    const int kbase = blockIdx.y * (NN / 2);
    const int lhi = lane >> 4, llo = lane & 15;

    f32x4 acc[2][4];
    #pragma unroll
    for (int mi = 0; mi < 2; ++mi)
        #pragma unroll
        for (int ni = 0; ni < 4; ++ni) acc[mi][ni] = (f32x4){0.f, 0.f, 0.f, 0.f};

    for (int kt = 0; kt < NN / 2; kt += 64) {
        float4 av[2];
        #pragma unroll
        for (int it = 0; it < 2; ++it) {
            int h = tid + 512 * it;
            int r = h >> 4, hs = h & 15, slot = hs >> 1, half = hs & 1;
            int gk = ((slot ^ (r & 7)) * 2 + half) * 4;
            av[it] = *(const float4*)(adj + (size_t)(i0 + r) * NN + kbase + kt + gk);
        }
        int4 bvh[4], bvl[4];
        #pragma unroll
        for (int it = 0; it < 4; ++it) {
            int u = tid + 512 * it;
            int c = u >> 3, s = u & 7;
            size_t off = (size_t)c * NN + kbase + kt + (s ^ (c & 7)) * 8;
            bvh[it] = *(const int4*)(YtH + off);
            bvl[it] = *(const int4*)(YtL + off);
        }
        __syncthreads();
        #pragma unroll
        for (int it = 0; it < 2; ++it) {
            int h = tid + 512 * it;
            short4 wh, wl;
            split_bf(av[it].x, wh.x, wl.x); split_bf(av[it].y, wh.y, wl.y);
            split_bf(av[it].z, wh.z, wl.z); split_bf(av[it].w, wh.w, wl.w);
            *(short4*)((char*)sAh + h * 8) = wh;
            *(short4*)((char*)sAl + h * 8) = wl;
        }
        #pragma unroll
        for (int it = 0; it < 4; ++it) {
            int u = tid + 512 * it;
            *(int4*)((char*)sBh + u * 16) = bvh[it];
            *(int4*)((char*)sBl + u * 16) = bvl[it];
        }
        __syncthreads();
        #pragma unroll
        for (int ks = 0; ks < 2; ++ks) {
            bf16x8 afh[2], afl[2], bfh[4], bfl[4];
            #pragma unroll
            for (int mi = 0; mi < 2; ++mi) {
                int R = wm * 32 + mi * 16 + llo;
                int boff = R * 128 + (((ks * 4 + lhi) ^ (R & 7)) << 4);
                afh[mi] = *(const bf16x8*)((const char*)sAh + boff);
                afl[mi] = *(const bf16x8*)((const char*)sAl + boff);
            }
            #pragma unroll
            for (int ni = 0; ni < 4; ++ni) {
                int Cc = wn * 64 + ni * 16 + llo;
                int boff = Cc * 128 + (((ks * 4 + lhi) ^ (Cc & 7)) << 4);
                bfh[ni] = *(const bf16x8*)((const char*)sBh + boff);
                bfl[ni] = *(const bf16x8*)((const char*)sBl + boff);
            }
            #pragma unroll
            for (int mi = 0; mi < 2; ++mi)
                #pragma unroll
                for (int ni = 0; ni < 4; ++ni) {
                    acc[mi][ni] = __builtin_amdgcn_mfma_f32_16x16x32_bf16(afh[mi], bfh[ni], acc[mi][ni], 0, 0, 0);
                    acc[mi][ni] = __builtin_amdgcn_mfma_f32_16x16x32_bf16(afh[mi], bfl[ni], acc[mi][ni], 0, 0, 0);
                    acc[mi][ni] = __builtin_amdgcn_mfma_f32_16x16x32_bf16(afl[mi], bfh[ni], acc[mi][ni], 0, 0, 0);
                }
        }
    }
    float* po = blockIdx.y == 0 ? part0 : part1;
    #pragma unroll
    for (int mi = 0; mi < 2; ++mi)
        #pragma unroll
        for (int ni = 0; ni < 4; ++ni) {
            int R0 = i0 + wm * 32 + mi * 16 + lhi * 4;
            int Cc = wn * 64 + ni * 16 + llo;
            #pragma unroll
            for (int r = 0; r < 4; ++r)
                po[(size_t)(R0 + r) * HF + Cc] = acc[mi][ni][r];
        }
}

// ---------------- H = elu((part0 + part1 + Y)/deg) ----------------
__global__ __launch_bounds__(256) void adj_reduce(const float* __restrict__ part0,
                                                  const float* __restrict__ part1,
                                                  const float* __restrict__ Y,
                                                  const float* __restrict__ deg,
                                                  float* __restrict__ H) {
    int idx = blockIdx.x * 256 + threadIdx.x;   // float4 index
    int i = idx >> 6;
    float4 p0 = ((const float4*)part0)[idx];
    float4 p1 = ((const float4*)part1)[idx];
    float4 y  = ((const float4*)Y)[idx];
    float dinv = 1.f / deg[i];
    float4 v;
    v.x = eluf((p0.x + p1.x + y.x) * dinv);
    v.y = eluf((p0.y + p1.y + y.y) * dinv);
    v.z = eluf((p0.z + p1.z + y.z) * dinv);
    v.w = eluf((p0.w + p1.w + y.w) * dinv);
    ((float4*)H)[idx] = v;
}

// ---------------- fp32 VALU GEMM (round-1, exact path) ----------------
__global__ __launch_bounds__(256) void gemm_ep(
    const float* __restrict__ A, const float* __restrict__ B,
    float* __restrict__ C, int M, int K, int N)
{
    __shared__ __align__(16) float sA[32][36];
    __shared__ __align__(16) float sB[32][256];
    const int tid  = threadIdx.x;
    const int row0 = blockIdx.x * 32;
    const int col0 = blockIdx.y * 256;
    const int r0 = (tid >> 6) * 8;
    const int c0 = (tid & 63) * 4;
    const int arow = tid >> 3;
    const int acol = (tid & 7) * 4;

    float acc[8][4];
    #pragma unroll
    for (int i = 0; i < 8; ++i)
        #pragma unroll
        for (int j = 0; j < 4; ++j) acc[i][j] = 0.f;

    for (int k0 = 0; k0 < K; k0 += 32) {
        float4 av = *(const float4*)(A + (size_t)(row0 + arow) * K + k0 + acol);
        float4 bv[8];
        #pragma unroll
        for (int i = 0; i < 8; ++i) {
            int idx = tid + i * 256;
            int br = idx >> 6, bc = (idx & 63) * 4;
            bv[i] = *(const float4*)(B + (size_t)(k0 + br) * N + col0 + bc);
        }
        __syncthreads();
        sA[acol + 0][arow] = av.x; sA[acol + 1][arow] = av.y;
        sA[acol + 2][arow] = av.z; sA[acol + 3][arow] = av.w;
        #pragma unroll
        for (int i = 0; i < 8; ++i) {
            int idx = tid + i * 256;
            int br = idx >> 6, bc = (idx & 63) * 4;
            *(float4*)&sB[br][bc] = bv[i];
        }
        __syncthreads();
        #pragma unroll 8
        for (int kk = 0; kk < 32; ++kk) {
            float4 a0 = *(const float4*)&sA[kk][r0];
            float4 a1 = *(const float4*)&sA[kk][r0 + 4];
            float4 b  = *(const float4*)&sB[kk][c0];
            float ar[8] = {a0.x, a0.y, a0.z, a0.w, a1.x, a1.y, a1.z, a1.w};
            float bc4[4] = {b.x, b.y, b.z, b.w};
            #pragma unroll
            for (int i = 0; i < 8; ++i)
                #pragma unroll
                for (int j = 0; j < 4; ++j)
                    acc[i][j] = fmaf(ar[i], bc4[j], acc[i][j]);
        }
    }
    #pragma unroll
    for (int i = 0; i < 8; ++i) {
        size_t off = (size_t)(row0 + r0 + i) * N + col0 + c0;
        *(float4*)(C + off) = make_float4(acc[i][0], acc[i][1], acc[i][2], acc[i][3]);
    }
}

// ---------------- wa2 = W @ a2 ----------------
__global__ __launch_bounds__(512) void wa2_kernel(const float* __restrict__ W,
                                                  const float* __restrict__ a2,
                                                  float* __restrict__ wa2) {
    int i = threadIdx.x;
    float s = 0.f;
    for (int j = 0; j < HF; ++j) s += W[(size_t)i * HF + j] * a2[j];
    wa2[i] = s;
}

// ---------------- s2 = x @ wa2 ----------------
__global__ __launch_bounds__(256) void s2_kernel(const float* __restrict__ x,
                                                 const float* __restrict__ wa2,
                                                 float* __restrict__ s2) {
    int lane = threadIdx.x & 63, wv = threadIdx.x >> 6;
    int row = blockIdx.x * 4 + wv;
    const float4* xr = (const float4*)(x + (size_t)row * FIN);
    const float4* w4 = (const float4*)wa2;
    float s = 0.f;
    #pragma unroll
    for (int t = 0; t < 2; ++t) {
        float4 a = xr[lane + 64 * t], b = w4[lane + 64 * t];
        s += a.x * b.x + a.y * b.y + a.z * b.z + a.w * b.w;
    }
    #pragma unroll
    for (int off = 32; off > 0; off >>= 1) s += __shfl_down(s, off);
    if (lane == 0) s2[row] = s;
}

// ---------------- top-16 of s2 ----------------
__global__ __launch_bounds__(256) void top16_kernel(const float* __restrict__ s2,
                                                    int* __restrict__ Tflag) {
    __shared__ float sv[NN];
    __shared__ float rv[256];
    __shared__ int   ri[256];
    int tid = threadIdx.x;
    for (int i = tid; i < NN; i += 256) sv[i] = s2[i];
    __syncthreads();
    for (int it = 0; it < 16; ++it) {
        float best = -INFINITY; int bi = NN;
        for (int i = tid; i < NN; i += 256) {
            float v = sv[i];
            if (v > best) { best = v; bi = i; }
        }
        rv[tid] = best; ri[tid] = bi;
        __syncthreads();
        for (int off = 128; off > 0; off >>= 1) {
            if (tid < off) {
                float v2 = rv[tid + off]; int i2 = ri[tid + off];
                if (v2 > rv[tid] || (v2 == rv[tid] && i2 < ri[tid])) {
                    rv[tid] = v2; ri[tid] = i2;
                }
            }
            __syncthreads();
        }
        if (tid == 0) { int wi = ri[0]; Tflag[wi] = 1; sv[wi] = -INFINITY; }
        __syncthreads();
    }
}

// ---------------- column sums of Y: total[k] and sum over T rows ----------------
__global__ __launch_bounds__(256) void colsum_T(const float* __restrict__ Y,
                                                const int* __restrict__ Tflag,
                                                float* __restrict__ total,
                                                float* __restrict__ sumT) {
    int k = threadIdx.x;
    int r0 = blockIdx.x * 128;
    float t = 0.f, tt = 0.f;
    for (int r = r0; r < r0 + 128; ++r) {
        float v = Y[(size_t)r * HF + k];
        t += v;
        if (Tflag[r]) tt += v;
    }
    atomicAdd(&total[k], t);
    atomicAdd(&sumT[k], tt);
}

// ---------------- GCN2 propagate+elu, in place ----------------
__global__ __launch_bounds__(256) void gcn2_combine(float* __restrict__ Y,
                                                    const int* __restrict__ Tflag,
                                                    const float* __restrict__ sumT,
                                                    const float* __restrict__ total) {
    int idx = blockIdx.x * 256 + threadIdx.x;
    int i = idx >> 8, k = idx & 255;
    float v;
    if (Tflag[i]) v = total[k] / 8192.0f;
    else          v = (sumT[k] + Y[idx]) / 17.0f;
    Y[idx] = v > 0.f ? v : expm1f(v);
}

// ---------------- bilinear head + per-edge loss term ----------------
__global__ __launch_bounds__(256) void bilinear_kernel(
    const float* __restrict__ XB, const float* __restrict__ H,
    const float* __restrict__ Hs, const int* __restrict__ src,
    const int* __restrict__ dst, const float* __restrict__ labels,
    const float* __restrict__ bil_b,
    float* __restrict__ out_logits, float* __restrict__ out_pred,
    float* __restrict__ partials)
{
    __shared__ float wterm[4];
    int lane = threadIdx.x & 63;
    int wv = threadIdx.x >> 6;
    int e = blockIdx.x * 4 + wv;
    int s = src[e], d = dst[e];
    const float4* xb = (const float4*)(XB + (size_t)s * 512);
    const float4* h1 = (const float4*)(H + (size_t)d * HF);
    const float4* h2 = (const float4*)(Hs + (size_t)d * HF);
    float4 a = xb[lane], b = h1[lane];
    float sum = a.x * b.x + a.y * b.y + a.z * b.z + a.w * b.w;
    a = xb[64 + lane]; b = h2[lane];
    sum += a.x * b.x + a.y * b.y + a.z * b.z + a.w * b.w;
    #pragma unroll
    for (int off = 32; off > 0; off >>= 1) sum += __shfl_down(sum, off);
    if (lane == 0) {
        float l = sum + bil_b[0];
        out_logits[e] = l;
        out_pred[e] = (l >= 0.f) ? 1.f : 0.f;
        float lab = labels[e];
        wterm[wv] = fmaxf(l, 0.f) - l * lab + log1pf(expf(-fabsf(l)));
    }
    __syncthreads();
    if (threadIdx.x == 0)
        partials[blockIdx.x] = wterm[0] + wterm[1] + wterm[2] + wterm[3];
}

__global__ __launch_bounds__(256) void loss_finalize(const float* __restrict__ partials,
                                                     float* __restrict__ out) {
    __shared__ float s[256];
    int tid = threadIdx.x;
    float t = 0.f;
    for (int i = tid; i < ME / 4; i += 256) t += partials[i];
    s[tid] = t; __syncthreads();
    for (int off = 128; off > 0; off >>= 1) {
        if (tid < off) s[tid] += s[tid + off];
        __syncthreads();
    }
    if (tid == 0) out[0] = s[0] * (1.0f / (float)ME);
}

// ---------------- launch ----------------
extern "C" void kernel_launch(void* const* d_in, const int* in_sizes, int n_in,
                              void* d_out, int out_size, void* d_ws, size_t ws_size,
                              hipStream_t stream) {
    const int*   src    = (const int*)d_in[0];
    const int*   dst    = (const int*)d_in[1];
    const float* labels = (const float*)d_in[2];
    const float* adj    = (const float*)d_in[3];
    const float* x      = (const float*)d_in[4];
    const float* W1_0   = (const float*)d_in[5];
    const float* W1_1   = (const float*)d_in[6];
    const float* W2_0   = (const float*)d_in[7];
    const float* W2_1   = (const float*)d_in[8];
    const float* W      = (const float*)d_in[9];
    const float* a2     = (const float*)d_in[11];   // a1 unused (monotone-invariant)
    const float* bilw   = (const float*)d_in[12];
    const float* bilb   = (const float*)d_in[13];

    float* w = (float*)d_ws;
    float* deg    = w + 0;                 // 8192
    float* s2v    = w + 8192;              // 8192
    float* wa2v   = w + 16384;             // 512
    float* sumT   = w + 16896;             // 256
    float* total  = w + 17152;             // 256
    float* sum2T  = w + 17408;             // 256
    float* tot2   = w + 17664;             // 256
    float* lossp  = w + 17920;             // 16384
    int*   Tflag  = (int*)(w + 34304);     // 8192
    short* W10tH  = (short*)(w + 42496);   // 131072 sh (65536 f)
    short* W10tL  = (short*)(w + 108032);
    short* W11tH  = (short*)(w + 173568);  // 65536 sh (32768 f)
    short* W11tL  = (short*)(w + 206336);
    float* bufY   = w + 239104;            // 2M f
    float* bufH   = w + 2336256;           // 2M f (also part0)
    float* bufHs  = w + 4433408;           // 2M f (also part1)
    float* R      = w + 6530560;           // 4M f: bufH1 | YbtH | YbtL, later XB
    float* bufH1  = R;                     // 2M f
    short* YbtH   = (short*)(R + 2097152); // 2M sh (1M f)
    short* YbtL   = (short*)(R + 3145728); // 2M sh (1M f)
    // total usage: 10,724,864 floats = 42.9 MB

    float* out       = (float*)d_out;
    float* out_logit = out + 1;
    float* out_pred  = out + 1 + ME;

    hipMemsetAsync(deg, 0, NN * sizeof(float), stream);
    hipMemsetAsync(sumT, 0, 1024 * sizeof(float), stream);
    hipMemsetAsync(Tflag, 0, NN * sizeof(int), stream);

    trans_w_split<<<512, 256, 0, stream>>>(W1_0, W10tH, W10tL, 512, 8);
    trans_w_split<<<256, 256, 0, stream>>>(W1_1, W11tH, W11tL, 256, 8);

    colsum_deg<<<dim3(32, 16), 256, 0, stream>>>(adj, deg);

    // ---- GCN1 (split-bf16 MFMA; errors damped by /deg ~ 4097) ----
    mfma_split<<<dim3(128, 2), 256, 0, stream>>>(x, W10tH, W10tL, bufY, YbtH, YbtL, NN, FIN, HF);
    adj_prop<<<dim3(128, 2), 512, 0, stream>>>(adj, YbtH, YbtL, bufH, bufHs);
    adj_reduce<<<2048, 256, 0, stream>>>(bufH, bufHs, bufY, deg, bufH1);
    mfma_split<<<dim3(128, 2), 256, 0, stream>>>(bufH1, W11tH, W11tL, bufY, YbtH, YbtL, NN, HF, HF);
    adj_prop<<<dim3(128, 2), 512, 0, stream>>>(adj, YbtH, YbtL, bufH, bufHs);
    adj_reduce<<<2048, 256, 0, stream>>>(bufH, bufHs, bufY, deg, bufH);   // bufH = H

    // ---- similarity graph (exact fp32 ordering) ----
    wa2_kernel<<<1, 512, 0, stream>>>(W, a2, wa2v);
    s2_kernel<<<NN / 4, 256, 0, stream>>>(x, wa2v, s2v);
    top16_kernel<<<1, 256, 0, stream>>>(s2v, Tflag);

    // ---- GCN2 (fp32, sign-critical: deg=17 gives no error damping) ----
    gemm_ep<<<dim3(256, 1), 256, 0, stream>>>(x, W2_0, bufY, NN, FIN, HF);
    colsum_T<<<64, 256, 0, stream>>>(bufY, Tflag, total, sumT);
    gcn2_combine<<<NN, 256, 0, stream>>>(bufY, Tflag, sumT, total);
    gemm_ep<<<dim3(256, 1), 256, 0, stream>>>(bufY, W2_1, bufHs, NN, HF, HF);
    colsum_T<<<64, 256, 0, stream>>>(bufHs, Tflag, tot2, sum2T);
    gcn2_combine<<<NN, 256, 0, stream>>>(bufHs, Tflag, sum2T, tot2);      // bufHs = H_

    // ---- bilinear head (fp32, sign-critical) ----
    gemm_ep<<<dim3(256, 2), 256, 0, stream>>>(x, bilw, R, NN, FIN, 512);  // R = XB
    bilinear_kernel<<<ME / 4, 256, 0, stream>>>(R, bufH, bufHs, src, dst, labels, bilb,
                                                out_logit, out_pred, lossp);
    loss_finalize<<<1, 256, 0, stream>>>(lossp, out);
}

// Round 5
// 1338.034 us; speedup vs baseline: 2.2558x; 1.0409x over previous
//
#include <hip/hip_runtime.h>
#include <math.h>

#define NN    8192
#define FIN   512
#define HF    256
#define ME    65536

typedef short bf16x8 __attribute__((ext_vector_type(8)));
typedef float f32x4  __attribute__((ext_vector_type(4)));

__device__ inline unsigned short f2bf(float f) {
    unsigned u = __builtin_bit_cast(unsigned, f);
    u += 0x7FFF + ((u >> 16) & 1);
    return (unsigned short)(u >> 16);
}
__device__ inline float bf2f(unsigned short h) {
    return __builtin_bit_cast(float, (unsigned)h << 16);
}
__device__ inline void split_bf(float v, short& hi, short& lo) {
    unsigned short h = f2bf(v);
    hi = (short)h;
    lo = (short)f2bf(v - bf2f(h));
}
__device__ inline float eluf(float v) { return v > 0.f ? v : expm1f(v); }

// ---------------- column sums of adj (+1 for self loop) -> deg ----------------
__global__ __launch_bounds__(256) void colsum_deg(const float* __restrict__ adj,
                                                  float* __restrict__ deg) {
    int c = blockIdx.x * 256 + threadIdx.x;
    int r0 = blockIdx.y * 256;
    float s = 0.f;
    for (int r = r0; r < r0 + 256; ++r) s += adj[(size_t)r * NN + c];
    if (blockIdx.y == 0) s += 1.f;
    atomicAdd(&deg[c], s);
}

// ---------------- W [K][N] fp32 -> split bf16 Wt_hi/lo [N][K] ----------------
__global__ __launch_bounds__(256) void trans_w_split(const float* __restrict__ src,
                                                     short* __restrict__ dsth,
                                                     short* __restrict__ dstl,
                                                     int K, int lgN) {
    int idx = blockIdx.x * 256 + threadIdx.x;
    int N = 1 << lgN;
    int k = idx >> lgN, n = idx & (N - 1);
    short h, l;
    split_bf(src[idx], h, l);
    dsth[(size_t)n * K + k] = h;
    dstl[(size_t)n * K + k] = l;
}

// ---------------- split-bf16 MFMA GEMM: C = A(fp32) @ Bt^T, + transposed split out
// BM=64, BN=128, BK=64, 256 threads (4 waves 2x2, wave tile 32x64)
__global__ __launch_bounds__(256) void mfma_split(
    const float* __restrict__ A, const short* __restrict__ BtH,
    const short* __restrict__ BtL, float* __restrict__ C,
    short* __restrict__ CtH, short* __restrict__ CtL, int M, int K, int N)
{
    __shared__ __align__(16) char smem[49152];
    short* sAh = (short*)smem;                 // 64*64
    short* sAl = (short*)(smem + 8192);
    short* sBh = (short*)(smem + 16384);       // 128*64
    short* sBl = (short*)(smem + 32768);
    float* sT  = (float*)smem;                 // 64*136 fp32 overlay (epilogue)
    const int tid = threadIdx.x, lane = tid & 63, wid = tid >> 6;
    const int wm = wid >> 1, wn = wid & 1;
    const int m0 = blockIdx.x * 64, n0 = blockIdx.y * 128;
    const int lhi = lane >> 4, llo = lane & 15;

    f32x4 acc[2][4];
    #pragma unroll
    for (int mi = 0; mi < 2; ++mi)
        #pragma unroll
        for (int ni = 0; ni < 4; ++ni) acc[mi][ni] = (f32x4){0.f, 0.f, 0.f, 0.f};

    for (int kt = 0; kt < K; kt += 64) {
        float4 av[4];
        #pragma unroll
        for (int it = 0; it < 4; ++it) {
            int h = tid + 256 * it;
            int r = h >> 4, hs = h & 15, slot = hs >> 1, half = hs & 1;
            int gk = ((slot ^ (r & 7)) * 2 + half) * 4;
            av[it] = *(const float4*)(A + (size_t)(m0 + r) * K + kt + gk);
        }
        int4 bvh[4], bvl[4];
        #pragma unroll
        for (int it = 0; it < 4; ++it) {
            int u = tid + 256 * it;
            int c = u >> 3, s = u & 7;
            size_t off = (size_t)(n0 + c) * K + kt + (s ^ (c & 7)) * 8;
            bvh[it] = *(const int4*)(BtH + off);
            bvl[it] = *(const int4*)(BtL + off);
        }
        __syncthreads();
        #pragma unroll
        for (int it = 0; it < 4; ++it) {
            int h = tid + 256 * it;
            short4 wh, wl;
            split_bf(av[it].x, wh.x, wl.x); split_bf(av[it].y, wh.y, wl.y);
            split_bf(av[it].z, wh.z, wl.z); split_bf(av[it].w, wh.w, wl.w);
            *(short4*)((char*)sAh + h * 8) = wh;
            *(short4*)((char*)sAl + h * 8) = wl;
        }
        #pragma unroll
        for (int it = 0; it < 4; ++it) {
            int u = tid + 256 * it;
            *(int4*)((char*)sBh + u * 16) = bvh[it];
            *(int4*)((char*)sBl + u * 16) = bvl[it];
        }
        __syncthreads();
        #pragma unroll
        for (int ks = 0; ks < 2; ++ks) {
            bf16x8 afh[2], afl[2], bfh[4], bfl[4];
            #pragma unroll
            for (int mi = 0; mi < 2; ++mi) {
                int R = wm * 32 + mi * 16 + llo;
                int boff = R * 128 + (((ks * 4 + lhi) ^ (R & 7)) << 4);
                afh[mi] = *(const bf16x8*)((const char*)sAh + boff);
                afl[mi] = *(const bf16x8*)((const char*)sAl + boff);
            }
            #pragma unroll
            for (int ni = 0; ni < 4; ++ni) {
                int Cc = wn * 64 + ni * 16 + llo;
                int boff = Cc * 128 + (((ks * 4 + lhi) ^ (Cc & 7)) << 4);
                bfh[ni] = *(const bf16x8*)((const char*)sBh + boff);
                bfl[ni] = *(const bf16x8*)((const char*)sBl + boff);
            }
            #pragma unroll
            for (int mi = 0; mi < 2; ++mi)
                #pragma unroll
                for (int ni = 0; ni < 4; ++ni) {
                    acc[mi][ni] = __builtin_amdgcn_mfma_f32_16x16x32_bf16(afh[mi], bfh[ni], acc[mi][ni], 0, 0, 0);
                    acc[mi][ni] = __builtin_amdgcn_mfma_f32_16x16x32_bf16(afh[mi], bfl[ni], acc[mi][ni], 0, 0, 0);
                    acc[mi][ni] = __builtin_amdgcn_mfma_f32_16x16x32_bf16(afl[mi], bfh[ni], acc[mi][ni], 0, 0, 0);
                }
        }
    }

    __syncthreads();   // LDS reads done; overlay sT
    #pragma unroll
    for (int mi = 0; mi < 2; ++mi)
        #pragma unroll
        for (int ni = 0; ni < 4; ++ni) {
            int lr = wm * 32 + mi * 16 + lhi * 4;
            int lc = wn * 64 + ni * 16 + llo;
            int R0 = m0 + lr;
            int Cc = n0 + lc;
            #pragma unroll
            for (int r = 0; r < 4; ++r) {
                C[(size_t)(R0 + r) * N + Cc] = acc[mi][ni][r];
                sT[(lr + r) * 136 + lc] = acc[mi][ni][r];
            }
        }
    __syncthreads();
    int c = tid >> 1, ih = (tid & 1) * 32;
    short bh[32], bl[32];
    #pragma unroll
    for (int j = 0; j < 32; ++j)
        split_bf(sT[(ih + j) * 136 + c], bh[j], bl[j]);
    int4* dh = (int4*)(CtH + (size_t)(n0 + c) * M + m0 + ih);
    int4* dl = (int4*)(CtL + (size_t)(n0 + c) * M + m0 + ih);
    #pragma unroll
    for (int q = 0; q < 4; ++q) { dh[q] = ((int4*)bh)[q]; dl[q] = ((int4*)bl)[q]; }
}

// ---------------- adj propagate partial (split-bf16), KSPLIT=4 --------------
// BM=64, BN=256(=HF), BK=64, 512 threads, grid 512 (1-D, XCD-aware decode)
// part[ky] = adj[:, kchunk_ky] @ Y[kchunk_ky, :]
__global__ __launch_bounds__(512) void adj_prop(const float* __restrict__ adj,
                                                const short* __restrict__ YtH,
                                                const short* __restrict__ YtL,
                                                float* part)
{
    __shared__ __align__(16) char smem[81920];
    short* sAh = (short*)smem;                 // 64*64
    short* sAl = (short*)(smem + 8192);
    short* sBh = (short*)(smem + 16384);       // 256*64
    short* sBl = (short*)(smem + 49152);
    const int tid = threadIdx.x, lane = tid & 63, wid = tid >> 6;
    const int wm = wid >> 2, wn = wid & 3;
    // XCD-aware decode: with round-robin bid->XCD, chunk ky owns XCD pair {2ky,2ky+1}
    const int bid = blockIdx.x;
    const int pxc = bid & 7;
    const int ky  = pxc >> 1;                  // 0..3 K-chunk
    const int bx  = ((bid >> 3) << 1) | (pxc & 1);   // 0..127 row-block
    const int i0 = bx * 64;
    const int kbase = ky * (NN / 4);
    const int lhi = lane >> 4, llo = lane & 15;

    f32x4 acc[2][4];
    #pragma unroll
    for (int mi = 0; mi < 2; ++mi)
        #pragma unroll
        for (int ni = 0; ni < 4; ++ni) acc[mi][ni] = (f32x4){0.f, 0.f, 0.f, 0.f};

    float4 av[2];
    int4 bvh[4], bvl[4];
    auto load_tile = [&](int kt) {
        #pragma unroll
        for (int it = 0; it < 2; ++it) {
            int h = tid + 512 * it;
            int r = h >> 4, hs = h & 15, slot = hs >> 1, half = hs & 1;
            int gk = ((slot ^ (r & 7)) * 2 + half) * 4;
            av[it] = *(const float4*)(adj + (size_t)(i0 + r) * NN + kbase + kt + gk);
        }
        #pragma unroll
        for (int it = 0; it < 4; ++it) {
            int u = tid + 512 * it;
            int c = u >> 3, s = u & 7;
            size_t off = (size_t)c * NN + kbase + kt + (s ^ (c & 7)) * 8;
            bvh[it] = *(const int4*)(YtH + off);
            bvl[it] = *(const int4*)(YtL + off);
        }
    };

    load_tile(0);
    for (int kt = 0; kt < NN / 4; kt += 64) {
        __syncthreads();            // previous tile's LDS reads done
        #pragma unroll
        for (int it = 0; it < 2; ++it) {
            int h = tid + 512 * it;
            short4 wh, wl;
            split_bf(av[it].x, wh.x, wl.x); split_bf(av[it].y, wh.y, wl.y);
            split_bf(av[it].z, wh.z, wl.z); split_bf(av[it].w, wh.w, wl.w);
            *(short4*)((char*)sAh + h * 8) = wh;
            *(short4*)((char*)sAl + h * 8) = wl;
        }
        #pragma unroll
        for (int it = 0; it < 4; ++it) {
            int u = tid + 512 * it;
            *(int4*)((char*)sBh + u * 16) = bvh[it];
            *(int4*)((char*)sBl + u * 16) = bvl[it];
        }
        __syncthreads();            // LDS ready
        if (kt + 64 < NN / 4) load_tile(kt + 64);   // issue next loads under MFMA
        #pragma unroll
        for (int ks = 0; ks < 2; ++ks) {
            bf16x8 afh[2], afl[2], bfh[4], bfl[4];
            #pragma unroll
            for (int mi = 0; mi < 2; ++mi) {
                int R = wm * 32 + mi * 16 + llo;
                int boff = R * 128 + (((ks * 4 + lhi) ^ (R & 7)) << 4);
                afh[mi] = *(const bf16x8*)((const char*)sAh + boff);
                afl[mi] = *(const bf16x8*)((const char*)sAl + boff);
            }
            #pragma unroll
            for (int ni = 0; ni < 4; ++ni) {
                int Cc = wn * 64 + ni * 16 + llo;
                int boff = Cc * 128 + (((ks * 4 + lhi) ^ (Cc & 7)) << 4);
                bfh[ni] = *(const bf16x8*)((const char*)sBh + boff);
                bfl[ni] = *(const bf16x8*)((const char*)sBl + boff);
            }
            #pragma unroll
            for (int mi = 0; mi < 2; ++mi)
                #pragma unroll
                for (int ni = 0; ni < 4; ++ni) {
                    acc[mi][ni] = __builtin_amdgcn_mfma_f32_16x16x32_bf16(afh[mi], bfh[ni], acc[mi][ni], 0, 0, 0);
                    acc[mi][ni] = __builtin_amdgcn_mfma_f32_16x16x32_bf16(afh[mi], bfl[ni], acc[mi][ni], 0, 0, 0);
                    acc[mi][ni] = __builtin_amdgcn_mfma_f32_16x16x32_bf16(afl[mi], bfh[ni], acc[mi][ni], 0, 0, 0);
                }
        }
    }
    float* po = part + (size_t)ky * ((size_t)NN * HF);
    #pragma unroll
    for (int mi = 0; mi < 2; ++mi)
        #pragma unroll
        for (int ni = 0; ni < 4; ++ni) {
            int R0 = i0 + wm * 32 + mi * 16 + lhi * 4;
            int Cc = wn * 64 + ni * 16 + llo;
            #pragma unroll
            for (int r = 0; r < 4; ++r)
                po[(size_t)(R0 + r) * HF + Cc] = acc[mi][ni][r];
        }
}

// ---------------- H = elu((sum of 4 parts + Y)/deg). H may alias a part chunk. --
__global__ __launch_bounds__(256) void adj_reduce(const float* part,
                                                  const float* __restrict__ Y,
                                                  const float* __restrict__ deg,
                                                  float* H) {
    int idx = blockIdx.x * 256 + threadIdx.x;   // float4 index
    int i = idx >> 6;
    const size_t Q = (size_t)NN * HF / 4;
    const float4* p = (const float4*)part;
    float4 p0 = p[idx], p1 = p[idx + Q], p2 = p[idx + 2 * Q], p3 = p[idx + 3 * Q];
    float4 y  = ((const float4*)Y)[idx];
    float dinv = 1.f / deg[i];
    float4 v;
    v.x = eluf((p0.x + p1.x + p2.x + p3.x + y.x) * dinv);
    v.y = eluf((p0.y + p1.y + p2.y + p3.y + y.y) * dinv);
    v.z = eluf((p0.z + p1.z + p2.z + p3.z + y.z) * dinv);
    v.w = eluf((p0.w + p1.w + p2.w + p3.w + y.w) * dinv);
    ((float4*)H)[idx] = v;
}

// ---------------- fp32 VALU GEMM, BM=64 BN=64 BK=32, 256 thr, 4x4/thread ------
__global__ __launch_bounds__(256) void gemm32(
    const float* __restrict__ A, const float* __restrict__ B,
    float* __restrict__ C, int M, int K, int N)
{
    __shared__ __align__(16) float sA[32][68];   // transposed: sA[k][m], m = 0..63 (+4 pad)
    __shared__ __align__(16) float sB[32][68];
    const int tid = threadIdx.x;
    const int r0 = blockIdx.x * 64, c0 = blockIdx.y * 64;
    const int tr = tid >> 4, tc = tid & 15;      // rows 4tr.., cols 4tc..
    float acc[4][4];
    #pragma unroll
    for (int i = 0; i < 4; ++i)
        #pragma unroll
        for (int j = 0; j < 4; ++j) acc[i][j] = 0.f;

    for (int k0 = 0; k0 < K; k0 += 32) {
        float4 av[2], bv[2];
        #pragma unroll
        for (int it = 0; it < 2; ++it) {
            int u = tid + it * 256;
            int rr = u >> 3, kk = (u & 7) * 4;
            av[it] = *(const float4*)(A + (size_t)(r0 + rr) * K + k0 + kk);
        }
        #pragma unroll
        for (int it = 0; it < 2; ++it) {
            int u = tid + it * 256;
            int br = u >> 4, bc = (u & 15) * 4;
            bv[it] = *(const float4*)(B + (size_t)(k0 + br) * N + c0 + bc);
        }
        __syncthreads();
        #pragma unroll
        for (int it = 0; it < 2; ++it) {
            int u = tid + it * 256;
            int rr = u >> 3, kk = (u & 7) * 4;
            sA[kk + 0][rr] = av[it].x; sA[kk + 1][rr] = av[it].y;
            sA[kk + 2][rr] = av[it].z; sA[kk + 3][rr] = av[it].w;
        }
        #pragma unroll
        for (int it = 0; it < 2; ++it) {
            int u = tid + it * 256;
            int br = u >> 4, bc = (u & 15) * 4;
            *(float4*)&sB[br][bc] = bv[it];
        }
        __syncthreads();
        #pragma unroll
        for (int kk = 0; kk < 32; ++kk) {
            float4 a = *(const float4*)&sA[kk][4 * tr];
            float4 b = *(const float4*)&sB[kk][4 * tc];
            float aa[4] = {a.x, a.y, a.z, a.w};
            float bb[4] = {b.x, b.y, b.z, b.w};
            #pragma unroll
            for (int i = 0; i < 4; ++i)
                #pragma unroll
                for (int j = 0; j < 4; ++j)
                    acc[i][j] = fmaf(aa[i], bb[j], acc[i][j]);
        }
        __syncthreads();
    }
    #pragma unroll
    for (int i = 0; i < 4; ++i) {
        size_t off = (size_t)(r0 + 4 * tr + i) * N + c0 + 4 * tc;
        *(float4*)(C + off) = make_float4(acc[i][0], acc[i][1], acc[i][2], acc[i][3]);
    }
}

// ---------------- wa2 = W @ a2 ----------------
__global__ __launch_bounds__(512) void wa2_kernel(const float* __restrict__ W,
                                                  const float* __restrict__ a2,
                                                  float* __restrict__ wa2) {
    int i = threadIdx.x;
    float s = 0.f;
    for (int j = 0; j < HF; ++j) s += W[(size_t)i * HF + j] * a2[j];
    wa2[i] = s;
}

// ---------------- s2 = x @ wa2 ----------------
__global__ __launch_bounds__(256) void s2_kernel(const float* __restrict__ x,
                                                 const float* __restrict__ wa2,
                                                 float* __restrict__ s2) {
    int lane = threadIdx.x & 63, wv = threadIdx.x >> 6;
    int row = blockIdx.x * 4 + wv;
    const float4* xr = (const float4*)(x + (size_t)row * FIN);
    const float4* w4 = (const float4*)wa2;
    float s = 0.f;
    #pragma unroll
    for (int t = 0; t < 2; ++t) {
        float4 a = xr[lane + 64 * t], b = w4[lane + 64 * t];
        s += a.x * b.x + a.y * b.y + a.z * b.z + a.w * b.w;
    }
    #pragma unroll
    for (int off = 32; off > 0; off >>= 1) s += __shfl_down(s, off);
    if (lane == 0) s2[row] = s;
}

// ---------------- top-16 of s2 ----------------
__global__ __launch_bounds__(256) void top16_kernel(const float* __restrict__ s2,
                                                    int* __restrict__ Tflag) {
    __shared__ float sv[NN];
    __shared__ float rv[256];
    __shared__ int   ri[256];
    int tid = threadIdx.x;
    for (int i = tid; i < NN; i += 256) sv[i] = s2[i];
    __syncthreads();
    for (int it = 0; it < 16; ++it) {
        float best = -INFINITY; int bi = NN;
        for (int i = tid; i < NN; i += 256) {
            float v = sv[i];
            if (v > best) { best = v; bi = i; }
        }
        rv[tid] = best; ri[tid] = bi;
        __syncthreads();
        for (int off = 128; off > 0; off >>= 1) {
            if (tid < off) {
                float v2 = rv[tid + off]; int i2 = ri[tid + off];
                if (v2 > rv[tid] || (v2 == rv[tid] && i2 < ri[tid])) {
                    rv[tid] = v2; ri[tid] = i2;
                }
            }
            __syncthreads();
        }
        if (tid == 0) { int wi = ri[0]; Tflag[wi] = 1; sv[wi] = -INFINITY; }
        __syncthreads();
    }
}

// ---------------- column sums of Y: total[k] and sum over T rows ----------------
__global__ __launch_bounds__(256) void colsum_T(const float* __restrict__ Y,
                                                const int* __restrict__ Tflag,
                                                float* __restrict__ total,
                                                float* __restrict__ sumT) {
    int k = threadIdx.x;
    int r0 = blockIdx.x * 128;
    float t = 0.f, tt = 0.f;
    for (int r = r0; r < r0 + 128; ++r) {
        float v = Y[(size_t)r * HF + k];
        t += v;
        if (Tflag[r]) tt += v;
    }
    atomicAdd(&total[k], t);
    atomicAdd(&sumT[k], tt);
}

// ---------------- GCN2 propagate+elu, in place ----------------
__global__ __launch_bounds__(256) void gcn2_combine(float* __restrict__ Y,
                                                    const int* __restrict__ Tflag,
                                                    const float* __restrict__ sumT,
                                                    const float* __restrict__ total) {
    int idx = blockIdx.x * 256 + threadIdx.x;
    int i = idx >> 8, k = idx & 255;
    float v;
    if (Tflag[i]) v = total[k] / 8192.0f;
    else          v = (sumT[k] + Y[idx]) / 17.0f;
    Y[idx] = v > 0.f ? v : expm1f(v);
}

// ---------------- bilinear head + per-edge loss term ----------------
__global__ __launch_bounds__(256) void bilinear_kernel(
    const float* __restrict__ XB, const float* __restrict__ H,
    const float* __restrict__ Hs, const int* __restrict__ src,
    const int* __restrict__ dst, const float* __restrict__ labels,
    const float* __restrict__ bil_b,
    float* __restrict__ out_logits, float* __restrict__ out_pred,
    float* __restrict__ partials)
{
    __shared__ float wterm[4];
    int lane = threadIdx.x & 63;
    int wv = threadIdx.x >> 6;
    int e = blockIdx.x * 4 + wv;
    int s = src[e], d = dst[e];
    const float4* xb = (const float4*)(XB + (size_t)s * 512);
    const float4* h1 = (const float4*)(H + (size_t)d * HF);
    const float4* h2 = (const float4*)(Hs + (size_t)d * HF);
    float4 a = xb[lane], b = h1[lane];
    float sum = a.x * b.x + a.y * b.y + a.z * b.z + a.w * b.w;
    a = xb[64 + lane]; b = h2[lane];
    sum += a.x * b.x + a.y * b.y + a.z * b.z + a.w * b.w;
    #pragma unroll
    for (int off = 32; off > 0; off >>= 1) sum += __shfl_down(sum, off);
    if (lane == 0) {
        float l = sum + bil_b[0];
        out_logits[e] = l;
        out_pred[e] = (l >= 0.f) ? 1.f : 0.f;
        float lab = labels[e];
        wterm[wv] = fmaxf(l, 0.f) - l * lab + log1pf(expf(-fabsf(l)));
    }
    __syncthreads();
    if (threadIdx.x == 0)
        partials[blockIdx.x] = wterm[0] + wterm[1] + wterm[2] + wterm[3];
}

__global__ __launch_bounds__(256) void loss_finalize(const float* __restrict__ partials,
                                                     float* __restrict__ out) {
    __shared__ float s[256];
    int tid = threadIdx.x;
    float t = 0.f;
    for (int i = tid; i < ME / 4; i += 256) t += partials[i];
    s[tid] = t; __syncthreads();
    for (int off = 128; off > 0; off >>= 1) {
        if (tid < off) s[tid] += s[tid + off];
        __syncthreads();
    }
    if (tid == 0) out[0] = s[0] * (1.0f / (float)ME);
}

// ---------------- launch ----------------
extern "C" void kernel_launch(void* const* d_in, const int* in_sizes, int n_in,
                              void* d_out, int out_size, void* d_ws, size_t ws_size,
                              hipStream_t stream) {
    const int*   src    = (const int*)d_in[0];
    const int*   dst    = (const int*)d_in[1];
    const float* labels = (const float*)d_in[2];
    const float* adj    = (const float*)d_in[3];
    const float* x      = (const float*)d_in[4];
    const float* W1_0   = (const float*)d_in[5];
    const float* W1_1   = (const float*)d_in[6];
    const float* W2_0   = (const float*)d_in[7];
    const float* W2_1   = (const float*)d_in[8];
    const float* W      = (const float*)d_in[9];
    const float* a2     = (const float*)d_in[11];   // a1 unused (monotone-invariant)
    const float* bilw   = (const float*)d_in[12];
    const float* bilb   = (const float*)d_in[13];

    float* w = (float*)d_ws;
    const size_t Q = (size_t)NN * HF;      // 2097152
    float* deg    = w + 0;                 // 8192
    float* s2v    = w + 8192;              // 8192
    float* wa2v   = w + 16384;             // 512
    float* sumT   = w + 16896;             // 256
    float* total  = w + 17152;             // 256
    float* sum2T  = w + 17408;             // 256
    float* tot2   = w + 17664;             // 256
    float* lossp  = w + 17920;             // 16384
    int*   Tflag  = (int*)(w + 34304);     // 8192
    short* W10tH  = (short*)(w + 42496);   // 131072 sh
    short* W10tL  = (short*)(w + 108032);
    short* W11tH  = (short*)(w + 173568);  // 65536 sh
    short* W11tL  = (short*)(w + 206336);
    float* bufY   = w + 239104;            // 2M f
    short* YbtH   = (short*)(w + 2336256); // 2M sh
    short* YbtL   = (short*)(w + 3384832); // 2M sh
    float* P      = w + 4433408;           // 4 x 2M f partials
    float* bufH1  = P;                     // alias chunk 0 (in-place reduce)
    float* bufH   = P + 2 * Q;             // alias chunk 2
    float* bufHs  = P + 3 * Q;             // alias chunk 3
    float* XB     = P;                     // alias chunks 0-1 (4M f)
    // high-water: 12,822,016 floats = 51.3 MB

    float* out       = (float*)d_out;
    float* out_logit = out + 1;
    float* out_pred  = out + 1 + ME;

    hipMemsetAsync(deg, 0, NN * sizeof(float), stream);
    hipMemsetAsync(sumT, 0, 1024 * sizeof(float), stream);
    hipMemsetAsync(Tflag, 0, NN * sizeof(int), stream);

    trans_w_split<<<512, 256, 0, stream>>>(W1_0, W10tH, W10tL, 512, 8);
    trans_w_split<<<256, 256, 0, stream>>>(W1_1, W11tH, W11tL, 256, 8);

    colsum_deg<<<dim3(32, 32), 256, 0, stream>>>(adj, deg);

    // ---- GCN1 (split-bf16 MFMA; errors damped by /deg ~ 4097) ----
    mfma_split<<<dim3(128, 2), 256, 0, stream>>>(x, W10tH, W10tL, bufY, YbtH, YbtL, NN, FIN, HF);
    adj_prop<<<512, 512, 0, stream>>>(adj, YbtH, YbtL, P);
    adj_reduce<<<2048, 256, 0, stream>>>(P, bufY, deg, bufH1);
    mfma_split<<<dim3(128, 2), 256, 0, stream>>>(bufH1, W11tH, W11tL, bufY, YbtH, YbtL, NN, HF, HF);
    adj_prop<<<512, 512, 0, stream>>>(adj, YbtH, YbtL, P);
    adj_reduce<<<2048, 256, 0, stream>>>(P, bufY, deg, bufH);   // bufH = H

    // ---- similarity graph (exact fp32 ordering) ----
    wa2_kernel<<<1, 512, 0, stream>>>(W, a2, wa2v);
    s2_kernel<<<NN / 4, 256, 0, stream>>>(x, wa2v, s2v);
    top16_kernel<<<1, 256, 0, stream>>>(s2v, Tflag);

    // ---- GCN2 (fp32, sign-critical: deg=17 gives no error damping) ----
    gemm32<<<dim3(128, 4), 256, 0, stream>>>(x, W2_0, bufY, NN, 512, 256);
    colsum_T<<<64, 256, 0, stream>>>(bufY, Tflag, total, sumT);
    gcn2_combine<<<NN, 256, 0, stream>>>(bufY, Tflag, sumT, total);
    gemm32<<<dim3(128, 4), 256, 0, stream>>>(bufY, W2_1, bufHs, NN, 256, 256);
    colsum_T<<<64, 256, 0, stream>>>(bufHs, Tflag, tot2, sum2T);
    gcn2_combine<<<NN, 256, 0, stream>>>(bufHs, Tflag, sum2T, tot2);  // bufHs = H_

    // ---- bilinear head (fp32, sign-critical) ----
    gemm32<<<dim3(128, 8), 256, 0, stream>>>(x, bilw, XB, NN, 512, 512);
    bilinear_kernel<<<ME / 4, 256, 0, stream>>>(XB, bufH, bufHs, src, dst, labels, bilb,
                                                out_logit, out_pred, lossp);
    loss_finalize<<<1, 256, 0, stream>>>(lossp, out);
}

// Round 6
// 1210.230 us; speedup vs baseline: 2.4940x; 1.1056x over previous
//
#include <hip/hip_runtime.h>
#include <math.h>

#define NN    8192
#define FIN   512
#define HF    256
#define ME    65536

typedef short bf16x8 __attribute__((ext_vector_type(8)));
typedef float f32x4  __attribute__((ext_vector_type(4)));

__device__ inline unsigned short f2bf(float f) {
    unsigned u = __builtin_bit_cast(unsigned, f);
    u += 0x7FFF + ((u >> 16) & 1);
    return (unsigned short)(u >> 16);
}
__device__ inline float bf2f(unsigned short h) {
    return __builtin_bit_cast(float, (unsigned)h << 16);
}
__device__ inline void split_bf(float v, short& hi, short& lo) {
    unsigned short h = f2bf(v);
    hi = (short)h;
    lo = (short)f2bf(v - bf2f(h));
}
__device__ inline float eluf(float v) { return v > 0.f ? v : expm1f(v); }

// ---------------- column sums of adj (+1 for self loop) -> deg ----------------
__global__ __launch_bounds__(256) void colsum_deg(const float* __restrict__ adj,
                                                  float* __restrict__ deg) {
    int c = blockIdx.x * 256 + threadIdx.x;
    int r0 = blockIdx.y * 256;
    float s = 0.f;
    for (int r = r0; r < r0 + 256; ++r) s += adj[(size_t)r * NN + c];
    if (blockIdx.y == 0) s += 1.f;
    atomicAdd(&deg[c], s);
}

// ---------------- W [K][N] fp32 -> split bf16 Wt_hi/lo [N][K] ----------------
__global__ __launch_bounds__(256) void trans_w_split(const float* __restrict__ src,
                                                     short* __restrict__ dsth,
                                                     short* __restrict__ dstl,
                                                     int K, int lgN) {
    int idx = blockIdx.x * 256 + threadIdx.x;
    int N = 1 << lgN;
    int k = idx >> lgN, n = idx & (N - 1);
    short h, l;
    split_bf(src[idx], h, l);
    dsth[(size_t)n * K + k] = h;
    dstl[(size_t)n * K + k] = l;
}

// ---------------- split-bf16 MFMA GEMM: C = A(fp32) @ Bt^T, + transposed split out
// BM=64, BN=128, BK=64, 256 threads (4 waves 2x2, wave tile 32x64)
__global__ __launch_bounds__(256) void mfma_split(
    const float* __restrict__ A, const short* __restrict__ BtH,
    const short* __restrict__ BtL, float* __restrict__ C,
    short* __restrict__ CtH, short* __restrict__ CtL, int M, int K, int N)
{
    __shared__ __align__(16) char smem[49152];
    short* sAh = (short*)smem;                 // 64*64
    short* sAl = (short*)(smem + 8192);
    short* sBh = (short*)(smem + 16384);       // 128*64
    short* sBl = (short*)(smem + 32768);
    float* sT  = (float*)smem;                 // 64*136 fp32 overlay (epilogue)
    const int tid = threadIdx.x, lane = tid & 63, wid = tid >> 6;
    const int wm = wid >> 1, wn = wid & 1;
    const int m0 = blockIdx.x * 64, n0 = blockIdx.y * 128;
    const int lhi = lane >> 4, llo = lane & 15;

    f32x4 acc[2][4];
    #pragma unroll
    for (int mi = 0; mi < 2; ++mi)
        #pragma unroll
        for (int ni = 0; ni < 4; ++ni) acc[mi][ni] = (f32x4){0.f, 0.f, 0.f, 0.f};

    for (int kt = 0; kt < K; kt += 64) {
        float4 av[4];
        #pragma unroll
        for (int it = 0; it < 4; ++it) {
            int h = tid + 256 * it;
            int r = h >> 4, hs = h & 15, slot = hs >> 1, half = hs & 1;
            int gk = ((slot ^ (r & 7)) * 2 + half) * 4;
            av[it] = *(const float4*)(A + (size_t)(m0 + r) * K + kt + gk);
        }
        int4 bvh[4], bvl[4];
        #pragma unroll
        for (int it = 0; it < 4; ++it) {
            int u = tid + 256 * it;
            int c = u >> 3, s = u & 7;
            size_t off = (size_t)(n0 + c) * K + kt + (s ^ (c & 7)) * 8;
            bvh[it] = *(const int4*)(BtH + off);
            bvl[it] = *(const int4*)(BtL + off);
        }
        __syncthreads();
        #pragma unroll
        for (int it = 0; it < 4; ++it) {
            int h = tid + 256 * it;
            short4 wh, wl;
            split_bf(av[it].x, wh.x, wl.x); split_bf(av[it].y, wh.y, wl.y);
            split_bf(av[it].z, wh.z, wl.z); split_bf(av[it].w, wh.w, wl.w);
            *(short4*)((char*)sAh + h * 8) = wh;
            *(short4*)((char*)sAl + h * 8) = wl;
        }
        #pragma unroll
        for (int it = 0; it < 4; ++it) {
            int u = tid + 256 * it;
            *(int4*)((char*)sBh + u * 16) = bvh[it];
            *(int4*)((char*)sBl + u * 16) = bvl[it];
        }
        __syncthreads();
        #pragma unroll
        for (int ks = 0; ks < 2; ++ks) {
            bf16x8 afh[2], afl[2], bfh[4], bfl[4];
            #pragma unroll
            for (int mi = 0; mi < 2; ++mi) {
                int R = wm * 32 + mi * 16 + llo;
                int boff = R * 128 + (((ks * 4 + lhi) ^ (R & 7)) << 4);
                afh[mi] = *(const bf16x8*)((const char*)sAh + boff);
                afl[mi] = *(const bf16x8*)((const char*)sAl + boff);
            }
            #pragma unroll
            for (int ni = 0; ni < 4; ++ni) {
                int Cc = wn * 64 + ni * 16 + llo;
                int boff = Cc * 128 + (((ks * 4 + lhi) ^ (Cc & 7)) << 4);
                bfh[ni] = *(const bf16x8*)((const char*)sBh + boff);
                bfl[ni] = *(const bf16x8*)((const char*)sBl + boff);
            }
            #pragma unroll
            for (int mi = 0; mi < 2; ++mi)
                #pragma unroll
                for (int ni = 0; ni < 4; ++ni) {
                    acc[mi][ni] = __builtin_amdgcn_mfma_f32_16x16x32_bf16(afh[mi], bfh[ni], acc[mi][ni], 0, 0, 0);
                    acc[mi][ni] = __builtin_amdgcn_mfma_f32_16x16x32_bf16(afh[mi], bfl[ni], acc[mi][ni], 0, 0, 0);
                    acc[mi][ni] = __builtin_amdgcn_mfma_f32_16x16x32_bf16(afl[mi], bfh[ni], acc[mi][ni], 0, 0, 0);
                }
        }
    }

    __syncthreads();   // LDS reads done; overlay sT
    #pragma unroll
    for (int mi = 0; mi < 2; ++mi)
        #pragma unroll
        for (int ni = 0; ni < 4; ++ni) {
            int lr = wm * 32 + mi * 16 + lhi * 4;
            int lc = wn * 64 + ni * 16 + llo;
            int R0 = m0 + lr;
            int Cc = n0 + lc;
            #pragma unroll
            for (int r = 0; r < 4; ++r) {
                C[(size_t)(R0 + r) * N + Cc] = acc[mi][ni][r];
                sT[(lr + r) * 136 + lc] = acc[mi][ni][r];
            }
        }
    __syncthreads();
    int c = tid >> 1, ih = (tid & 1) * 32;
    short bh[32], bl[32];
    #pragma unroll
    for (int j = 0; j < 32; ++j)
        split_bf(sT[(ih + j) * 136 + c], bh[j], bl[j]);
    int4* dh = (int4*)(CtH + (size_t)(n0 + c) * M + m0 + ih);
    int4* dl = (int4*)(CtL + (size_t)(n0 + c) * M + m0 + ih);
    #pragma unroll
    for (int q = 0; q < 4; ++q) { dh[q] = ((int4*)bh)[q]; dl[q] = ((int4*)bl)[q]; }
}

// ---------------- fused adj propagate (split-bf16), single pass over K=8192 ---
// H[i][c] = elu((adj[i,:]@Y[:,c] + Y[i][c]) / deg[i])
// BM=64, BN=64, BK=64, 256 threads (4 waves 2x2, wave tile 32x32), grid 512.
// Block decode groups the 4 bn-blocks of each bm on one XCD (adj L2-dedup).
__global__ __launch_bounds__(256) void adj_fuse(const float* __restrict__ adj,
                                                const short* __restrict__ YtH,
                                                const short* __restrict__ YtL,
                                                const float* __restrict__ Y,
                                                const float* __restrict__ deg,
                                                float* __restrict__ H)
{
    __shared__ __align__(16) char smem[32768];
    short* sAh = (short*)smem;                 // 64*64
    short* sAl = (short*)(smem + 8192);
    short* sBh = (short*)(smem + 16384);       // 64*64
    short* sBl = (short*)(smem + 24576);
    const int tid = threadIdx.x, lane = tid & 63, wid = tid >> 6;
    const int wm = wid >> 1, wn = wid & 1;
    const int g = blockIdx.x & 7, sB_ = blockIdx.x >> 3;   // XCD, slot
    const int bm = g * 16 + (sB_ >> 2), bn = sB_ & 3;
    const int i0 = bm * 64, c0 = bn * 64;
    const int lhi = lane >> 4, llo = lane & 15;

    f32x4 acc[2][2];
    #pragma unroll
    for (int mi = 0; mi < 2; ++mi)
        #pragma unroll
        for (int ni = 0; ni < 2; ++ni) acc[mi][ni] = (f32x4){0.f, 0.f, 0.f, 0.f};

    float4 av[4];
    int4 bvh[2], bvl[2];
    auto load_tile = [&](int kt) {
        #pragma unroll
        for (int it = 0; it < 4; ++it) {
            int h = tid + 256 * it;
            int r = h >> 4, hs = h & 15, slot = hs >> 1, half = hs & 1;
            int gk = ((slot ^ (r & 7)) * 2 + half) * 4;
            av[it] = *(const float4*)(adj + (size_t)(i0 + r) * NN + kt + gk);
        }
        #pragma unroll
        for (int it = 0; it < 2; ++it) {
            int u = tid + 256 * it;
            int c = u >> 3, s = u & 7;
            size_t off = (size_t)(c0 + c) * NN + kt + (s ^ (c & 7)) * 8;
            bvh[it] = *(const int4*)(YtH + off);
            bvl[it] = *(const int4*)(YtL + off);
        }
    };

    load_tile(0);
    for (int kt = 0; kt < NN; kt += 64) {
        __syncthreads();            // previous tile's LDS reads done
        #pragma unroll
        for (int it = 0; it < 4; ++it) {
            int h = tid + 256 * it;
            short4 wh, wl;
            split_bf(av[it].x, wh.x, wl.x); split_bf(av[it].y, wh.y, wl.y);
            split_bf(av[it].z, wh.z, wl.z); split_bf(av[it].w, wh.w, wl.w);
            *(short4*)((char*)sAh + h * 8) = wh;
            *(short4*)((char*)sAl + h * 8) = wl;
        }
        #pragma unroll
        for (int it = 0; it < 2; ++it) {
            int u = tid + 256 * it;
            *(int4*)((char*)sBh + u * 16) = bvh[it];
            *(int4*)((char*)sBl + u * 16) = bvl[it];
        }
        __syncthreads();            // LDS ready
        if (kt + 64 < NN) load_tile(kt + 64);   // next loads fly under MFMA
        #pragma unroll
        for (int ks = 0; ks < 2; ++ks) {
            bf16x8 afh[2], afl[2], bfh[2], bfl[2];
            #pragma unroll
            for (int mi = 0; mi < 2; ++mi) {
                int R = wm * 32 + mi * 16 + llo;
                int boff = R * 128 + (((ks * 4 + lhi) ^ (R & 7)) << 4);
                afh[mi] = *(const bf16x8*)((const char*)sAh + boff);
                afl[mi] = *(const bf16x8*)((const char*)sAl + boff);
            }
            #pragma unroll
            for (int ni = 0; ni < 2; ++ni) {
                int Cc = wn * 32 + ni * 16 + llo;
                int boff = Cc * 128 + (((ks * 4 + lhi) ^ (Cc & 7)) << 4);
                bfh[ni] = *(const bf16x8*)((const char*)sBh + boff);
                bfl[ni] = *(const bf16x8*)((const char*)sBl + boff);
            }
            #pragma unroll
            for (int mi = 0; mi < 2; ++mi)
                #pragma unroll
                for (int ni = 0; ni < 2; ++ni) {
                    acc[mi][ni] = __builtin_amdgcn_mfma_f32_16x16x32_bf16(afh[mi], bfh[ni], acc[mi][ni], 0, 0, 0);
                    acc[mi][ni] = __builtin_amdgcn_mfma_f32_16x16x32_bf16(afh[mi], bfl[ni], acc[mi][ni], 0, 0, 0);
                    acc[mi][ni] = __builtin_amdgcn_mfma_f32_16x16x32_bf16(afl[mi], bfh[ni], acc[mi][ni], 0, 0, 0);
                }
        }
    }

    // fused epilogue: sT transpose -> coalesced float4 out with +Y, /deg, elu
    __syncthreads();
    float* sT = (float*)smem;                  // 64 x 68 fp32 (17.4 KB)
    #pragma unroll
    for (int mi = 0; mi < 2; ++mi)
        #pragma unroll
        for (int ni = 0; ni < 2; ++ni) {
            int lr = wm * 32 + mi * 16 + lhi * 4;
            int lc = wn * 32 + ni * 16 + llo;
            #pragma unroll
            for (int r = 0; r < 4; ++r)
                sT[(lr + r) * 68 + lc] = acc[mi][ni][r];
        }
    __syncthreads();
    int row = tid >> 2, quad = tid & 3;        // row 0..63, 16 cols per quad
    float dinv = 1.f / deg[i0 + row];
    const float4* yrow = (const float4*)(Y + (size_t)(i0 + row) * HF + c0 + quad * 16);
    float4* hrow = (float4*)(H + (size_t)(i0 + row) * HF + c0 + quad * 16);
    #pragma unroll
    for (int q = 0; q < 4; ++q) {
        float4 p = *(const float4*)&sT[row * 68 + quad * 16 + q * 4];
        float4 y = yrow[q];
        float4 v;
        v.x = eluf((p.x + y.x) * dinv);
        v.y = eluf((p.y + y.y) * dinv);
        v.z = eluf((p.z + y.z) * dinv);
        v.w = eluf((p.w + y.w) * dinv);
        hrow[q] = v;
    }
}

// ---------------- fp32 VALU GEMM, BM=64 BN=64 BK=32, 256 thr, 4x4/thread ------
__global__ __launch_bounds__(256) void gemm32(
    const float* __restrict__ A, const float* __restrict__ B,
    float* __restrict__ C, int M, int K, int N)
{
    __shared__ __align__(16) float sA[32][68];   // transposed: sA[k][m], m=0..63 (+4 pad)
    __shared__ __align__(16) float sB[32][68];
    const int tid = threadIdx.x;
    const int r0 = blockIdx.x * 64, c0 = blockIdx.y * 64;
    const int tr = tid >> 4, tc = tid & 15;
    float acc[4][4];
    #pragma unroll
    for (int i = 0; i < 4; ++i)
        #pragma unroll
        for (int j = 0; j < 4; ++j) acc[i][j] = 0.f;

    for (int k0 = 0; k0 < K; k0 += 32) {
        float4 av[2], bv[2];
        #pragma unroll
        for (int it = 0; it < 2; ++it) {
            int u = tid + it * 256;
            int rr = u >> 3, kk = (u & 7) * 4;
            av[it] = *(const float4*)(A + (size_t)(r0 + rr) * K + k0 + kk);
        }
        #pragma unroll
        for (int it = 0; it < 2; ++it) {
            int u = tid + it * 256;
            int br = u >> 4, bc = (u & 15) * 4;
            bv[it] = *(const float4*)(B + (size_t)(k0 + br) * N + c0 + bc);
        }
        __syncthreads();
        #pragma unroll
        for (int it = 0; it < 2; ++it) {
            int u = tid + it * 256;
            int rr = u >> 3, kk = (u & 7) * 4;
            sA[kk + 0][rr] = av[it].x; sA[kk + 1][rr] = av[it].y;
            sA[kk + 2][rr] = av[it].z; sA[kk + 3][rr] = av[it].w;
        }
        #pragma unroll
        for (int it = 0; it < 2; ++it) {
            int u = tid + it * 256;
            int br = u >> 4, bc = (u & 15) * 4;
            *(float4*)&sB[br][bc] = bv[it];
        }
        __syncthreads();
        #pragma unroll
        for (int kk = 0; kk < 32; ++kk) {
            float4 a = *(const float4*)&sA[kk][4 * tr];
            float4 b = *(const float4*)&sB[kk][4 * tc];
            float aa[4] = {a.x, a.y, a.z, a.w};
            float bb[4] = {b.x, b.y, b.z, b.w};
            #pragma unroll
            for (int i = 0; i < 4; ++i)
                #pragma unroll
                for (int j = 0; j < 4; ++j)
                    acc[i][j] = fmaf(aa[i], bb[j], acc[i][j]);
        }
        __syncthreads();
    }
    #pragma unroll
    for (int i = 0; i < 4; ++i) {
        size_t off = (size_t)(r0 + 4 * tr + i) * N + c0 + 4 * tc;
        *(float4*)(C + off) = make_float4(acc[i][0], acc[i][1], acc[i][2], acc[i][3]);
    }
}

// ---------------- wa2 = W @ a2 ----------------
__global__ __launch_bounds__(512) void wa2_kernel(const float* __restrict__ W,
                                                  const float* __restrict__ a2,
                                                  float* __restrict__ wa2) {
    int i = threadIdx.x;
    float s = 0.f;
    for (int j = 0; j < HF; ++j) s += W[(size_t)i * HF + j] * a2[j];
    wa2[i] = s;
}

// ---------------- s2 = x @ wa2 ----------------
__global__ __launch_bounds__(256) void s2_kernel(const float* __restrict__ x,
                                                 const float* __restrict__ wa2,
                                                 float* __restrict__ s2) {
    int lane = threadIdx.x & 63, wv = threadIdx.x >> 6;
    int row = blockIdx.x * 4 + wv;
    const float4* xr = (const float4*)(x + (size_t)row * FIN);
    const float4* w4 = (const float4*)wa2;
    float s = 0.f;
    #pragma unroll
    for (int t = 0; t < 2; ++t) {
        float4 a = xr[lane + 64 * t], b = w4[lane + 64 * t];
        s += a.x * b.x + a.y * b.y + a.z * b.z + a.w * b.w;
    }
    #pragma unroll
    for (int off = 32; off > 0; off >>= 1) s += __shfl_down(s, off);
    if (lane == 0) s2[row] = s;
}

// ---------------- top-16 of s2 ----------------
__global__ __launch_bounds__(256) void top16_kernel(const float* __restrict__ s2,
                                                    int* __restrict__ Tflag) {
    __shared__ float sv[NN];
    __shared__ float rv[256];
    __shared__ int   ri[256];
    int tid = threadIdx.x;
    for (int i = tid; i < NN; i += 256) sv[i] = s2[i];
    __syncthreads();
    for (int it = 0; it < 16; ++it) {
        float best = -INFINITY; int bi = NN;
        for (int i = tid; i < NN; i += 256) {
            float v = sv[i];
            if (v > best) { best = v; bi = i; }
        }
        rv[tid] = best; ri[tid] = bi;
        __syncthreads();
        for (int off = 128; off > 0; off >>= 1) {
            if (tid < off) {
                float v2 = rv[tid + off]; int i2 = ri[tid + off];
                if (v2 > rv[tid] || (v2 == rv[tid] && i2 < ri[tid])) {
                    rv[tid] = v2; ri[tid] = i2;
                }
            }
            __syncthreads();
        }
        if (tid == 0) { int wi = ri[0]; Tflag[wi] = 1; sv[wi] = -INFINITY; }
        __syncthreads();
    }
}

// ---------------- column sums of Y: total[k] and sum over T rows ----------------
__global__ __launch_bounds__(256) void colsum_T(const float* __restrict__ Y,
                                                const int* __restrict__ Tflag,
                                                float* __restrict__ total,
                                                float* __restrict__ sumT) {
    int k = threadIdx.x;
    int r0 = blockIdx.x * 128;
    float t = 0.f, tt = 0.f;
    for (int r = r0; r < r0 + 128; ++r) {
        float v = Y[(size_t)r * HF + k];
        t += v;
        if (Tflag[r]) tt += v;
    }
    atomicAdd(&total[k], t);
    atomicAdd(&sumT[k], tt);
}

// ---------------- GCN2 propagate+elu, in place ----------------
__global__ __launch_bounds__(256) void gcn2_combine(float* __restrict__ Y,
                                                    const int* __restrict__ Tflag,
                                                    const float* __restrict__ sumT,
                                                    const float* __restrict__ total) {
    int idx = blockIdx.x * 256 + threadIdx.x;
    int i = idx >> 8, k = idx & 255;
    float v;
    if (Tflag[i]) v = total[k] / 8192.0f;
    else          v = (sumT[k] + Y[idx]) / 17.0f;
    Y[idx] = v > 0.f ? v : expm1f(v);
}

// ---------------- bilinear head + per-edge loss term ----------------
__global__ __launch_bounds__(256) void bilinear_kernel(
    const float* __restrict__ XB, const float* __restrict__ H,
    const float* __restrict__ Hs, const int* __restrict__ src,
    const int* __restrict__ dst, const float* __restrict__ labels,
    const float* __restrict__ bil_b,
    float* __restrict__ out_logits, float* __restrict__ out_pred,
    float* __restrict__ partials)
{
    __shared__ float wterm[4];
    int lane = threadIdx.x & 63;
    int wv = threadIdx.x >> 6;
    int e = blockIdx.x * 4 + wv;
    int s = src[e], d = dst[e];
    const float4* xb = (const float4*)(XB + (size_t)s * 512);
    const float4* h1 = (const float4*)(H + (size_t)d * HF);
    const float4* h2 = (const float4*)(Hs + (size_t)d * HF);
    float4 a = xb[lane], b = h1[lane];
    float sum = a.x * b.x + a.y * b.y + a.z * b.z + a.w * b.w;
    a = xb[64 + lane]; b = h2[lane];
    sum += a.x * b.x + a.y * b.y + a.z * b.z + a.w * b.w;
    #pragma unroll
    for (int off = 32; off > 0; off >>= 1) sum += __shfl_down(sum, off);
    if (lane == 0) {
        float l = sum + bil_b[0];
        out_logits[e] = l;
        out_pred[e] = (l >= 0.f) ? 1.f : 0.f;
        float lab = labels[e];
        wterm[wv] = fmaxf(l, 0.f) - l * lab + log1pf(expf(-fabsf(l)));
    }
    __syncthreads();
    if (threadIdx.x == 0)
        partials[blockIdx.x] = wterm[0] + wterm[1] + wterm[2] + wterm[3];
}

__global__ __launch_bounds__(256) void loss_finalize(const float* __restrict__ partials,
                                                     float* __restrict__ out) {
    __shared__ float s[256];
    int tid = threadIdx.x;
    float t = 0.f;
    for (int i = tid; i < ME / 4; i += 256) t += partials[i];
    s[tid] = t; __syncthreads();
    for (int off = 128; off > 0; off >>= 1) {
        if (tid < off) s[tid] += s[tid + off];
        __syncthreads();
    }
    if (tid == 0) out[0] = s[0] * (1.0f / (float)ME);
}

// ---------------- launch ----------------
extern "C" void kernel_launch(void* const* d_in, const int* in_sizes, int n_in,
                              void* d_out, int out_size, void* d_ws, size_t ws_size,
                              hipStream_t stream) {
    const int*   src    = (const int*)d_in[0];
    const int*   dst    = (const int*)d_in[1];
    const float* labels = (const float*)d_in[2];
    const float* adj    = (const float*)d_in[3];
    const float* x      = (const float*)d_in[4];
    const float* W1_0   = (const float*)d_in[5];
    const float* W1_1   = (const float*)d_in[6];
    const float* W2_0   = (const float*)d_in[7];
    const float* W2_1   = (const float*)d_in[8];
    const float* W      = (const float*)d_in[9];
    const float* a2     = (const float*)d_in[11];   // a1 unused (monotone-invariant)
    const float* bilw   = (const float*)d_in[12];
    const float* bilb   = (const float*)d_in[13];

    float* w = (float*)d_ws;
    float* deg    = w + 0;                 // 8192
    float* s2v    = w + 8192;              // 8192
    float* wa2v   = w + 16384;             // 512
    float* sumT   = w + 16896;             // 256
    float* total  = w + 17152;             // 256
    float* sum2T  = w + 17408;             // 256
    float* tot2   = w + 17664;             // 256
    float* lossp  = w + 17920;             // 16384
    int*   Tflag  = (int*)(w + 34304);     // 8192
    short* W10tH  = (short*)(w + 42496);   // 131072 sh
    short* W10tL  = (short*)(w + 108032);
    short* W11tH  = (short*)(w + 173568);  // 65536 sh
    short* W11tL  = (short*)(w + 206336);
    float* bufY   = w + 239104;            // 2M f
    short* YbtH   = (short*)(w + 2336256); // 2M sh
    short* YbtL   = (short*)(w + 3384832); // 2M sh
    float* bufH1  = w + 4433408;           // 2M f
    float* bufH   = w + 6530560;           // 2M f
    float* bufHs  = w + 8627712;           // 2M f
    float* XB     = bufY;                  // overlays bufY+YbtH+YbtL (4M f, dead by then)
    // high-water: 10,724,864 floats = 42.9 MB (same as round-3 proven footprint)

    float* out       = (float*)d_out;
    float* out_logit = out + 1;
    float* out_pred  = out + 1 + ME;

    hipMemsetAsync(deg, 0, NN * sizeof(float), stream);
    hipMemsetAsync(sumT, 0, 1024 * sizeof(float), stream);
    hipMemsetAsync(Tflag, 0, NN * sizeof(int), stream);

    trans_w_split<<<512, 256, 0, stream>>>(W1_0, W10tH, W10tL, 512, 8);
    trans_w_split<<<256, 256, 0, stream>>>(W1_1, W11tH, W11tL, 256, 8);

    colsum_deg<<<dim3(32, 32), 256, 0, stream>>>(adj, deg);

    // ---- GCN1 (split-bf16 MFMA; errors damped by /deg ~ 4097) ----
    mfma_split<<<dim3(128, 2), 256, 0, stream>>>(x, W10tH, W10tL, bufY, YbtH, YbtL, NN, FIN, HF);
    adj_fuse<<<512, 256, 0, stream>>>(adj, YbtH, YbtL, bufY, deg, bufH1);
    mfma_split<<<dim3(128, 2), 256, 0, stream>>>(bufH1, W11tH, W11tL, bufY, YbtH, YbtL, NN, HF, HF);
    adj_fuse<<<512, 256, 0, stream>>>(adj, YbtH, YbtL, bufY, deg, bufH);   // bufH = H

    // ---- similarity graph (exact fp32 ordering) ----
    wa2_kernel<<<1, 512, 0, stream>>>(W, a2, wa2v);
    s2_kernel<<<NN / 4, 256, 0, stream>>>(x, wa2v, s2v);
    top16_kernel<<<1, 256, 0, stream>>>(s2v, Tflag);

    // ---- GCN2 (fp32, sign-critical: deg=17 gives no error damping) ----
    gemm32<<<dim3(128, 4), 256, 0, stream>>>(x, W2_0, bufY, NN, 512, 256);
    colsum_T<<<64, 256, 0, stream>>>(bufY, Tflag, total, sumT);
    gcn2_combine<<<NN, 256, 0, stream>>>(bufY, Tflag, sumT, total);
    gemm32<<<dim3(128, 4), 256, 0, stream>>>(bufY, W2_1, bufHs, NN, 256, 256);
    colsum_T<<<64, 256, 0, stream>>>(bufHs, Tflag, tot2, sum2T);
    gcn2_combine<<<NN, 256, 0, stream>>>(bufHs, Tflag, sum2T, tot2);  // bufHs = H_

    // ---- bilinear head (fp32, sign-critical); XB overlays dead bufY/Ybt ----
    gemm32<<<dim3(128, 8), 256, 0, stream>>>(x, bilw, XB, NN, 512, 512);
    bilinear_kernel<<<ME / 4, 256, 0, stream>>>(XB, bufH, bufHs, src, dst, labels, bilb,
                                                out_logit, out_pred, lossp);
    loss_finalize<<<1, 256, 0, stream>>>(lossp, out);
}